// Round 1
// baseline (250.967 us; speedup 1.0000x reference)
//
#include <hip/hip_runtime.h>
#include <hip/hip_bf16.h>

// Problem constants (SparseMoE: D=512, H=2048, O=512, E=8, K=2, CF=1.0)
#define NTOK 16384
#define DDIM 512
#define HDIM 2048
#define ODIM 512
#define NE 8
#define CAP 2048   // max(int(N/E*CF), 4) = 2048

typedef __attribute__((ext_vector_type(8))) short short8v;
typedef __attribute__((ext_vector_type(8))) unsigned short ushort8v;
typedef __attribute__((ext_vector_type(4))) float f32x4;

static __device__ __forceinline__ unsigned short f2bf(float f) {
  __hip_bfloat16 h = __float2bfloat16(f);
  return __builtin_bit_cast(unsigned short, h);
}

// XOR-swizzled LDS address (row-major [128][64] bf16, 128B rows).
// Breaks the 16-rows-same-bank conflict on ds_read_b128 (G4 pattern).
static __device__ __forceinline__ int swz(int row, int kb) {
  return (row << 7) + (kb ^ ((row & 7) << 4));
}

// ---------------- transpose + f32->bf16 convert: (E,R,C) f32 -> (E,C,R) bf16
__global__ void k_transpose_cvt(const float* __restrict__ src,
                                __hip_bfloat16* __restrict__ dst, int R, int C) {
  __shared__ float tile[32][33];
  int e = blockIdx.z;
  size_t base = (size_t)e * R * C;
  int c0 = blockIdx.x * 32, r0 = blockIdx.y * 32;
  int tx = threadIdx.x, ty = threadIdx.y;
#pragma unroll
  for (int i = 0; i < 32; i += 8)
    tile[ty + i][tx] = src[base + (size_t)(r0 + ty + i) * C + c0 + tx];
  __syncthreads();
#pragma unroll
  for (int i = 0; i < 32; i += 8)
    dst[base + (size_t)(c0 + ty + i) * R + r0 + tx] = __float2bfloat16(tile[tx][ty + i]);
}

// ---------------- gating: logits, softmax (f32), top-2 + normalized weights
__global__ void k_gate(const float* __restrict__ x, const float* __restrict__ gw,
                       const float* __restrict__ gb, float* __restrict__ gate_probs,
                       int2* __restrict__ tk_e, float2* __restrict__ tk_w,
                       int* __restrict__ token_slot) {
  __shared__ float gws[DDIM * 9];  // pad 8->9 floats per row: bank-conflict-free
  int tid = threadIdx.x;
  for (int i = tid; i < DDIM * NE; i += 256) {
    int d = i >> 3, e = i & 7;
    gws[d * 9 + e] = gw[i];
  }
  __syncthreads();
  int wid = tid >> 6, lane = tid & 63;
  int t = blockIdx.x * 4 + wid;
  const float* xr = x + (size_t)t * DDIM;
  float acc[NE] = {0.f, 0.f, 0.f, 0.f, 0.f, 0.f, 0.f, 0.f};
#pragma unroll
  for (int j = 0; j < 8; ++j) {
    float xv = xr[lane + 64 * j];            // 256B coalesced per instr
    const float* g = &gws[(lane + 64 * j) * 9];
#pragma unroll
    for (int e = 0; e < NE; ++e) acc[e] += xv * g[e];
  }
#pragma unroll
  for (int e = 0; e < NE; ++e) {
#pragma unroll
    for (int off = 32; off > 0; off >>= 1) acc[e] += __shfl_xor(acc[e], off, 64);
  }
  if (lane == 0) {
    float p[NE];
    float m = -1e30f;
#pragma unroll
    for (int e = 0; e < NE; ++e) { p[e] = acc[e] + gb[e]; m = fmaxf(m, p[e]); }
    float s = 0.f;
#pragma unroll
    for (int e = 0; e < NE; ++e) { p[e] = expf(p[e] - m); s += p[e]; }
    float inv = 1.f / s;
#pragma unroll
    for (int e = 0; e < NE; ++e) { p[e] *= inv; gate_probs[(size_t)t * NE + e] = p[e]; }
    // top-2, ties -> lower index (strict > replacement matches jax top_k)
    int i1 = 0; float p1 = p[0];
#pragma unroll
    for (int e = 1; e < NE; ++e) if (p[e] > p1) { p1 = p[e]; i1 = e; }
    int i2 = -1; float p2 = -1e30f;
#pragma unroll
    for (int e = 0; e < NE; ++e) if (e != i1 && p[e] > p2) { p2 = p[e]; i2 = e; }
    float wsum = p1 + p2;
    tk_e[t] = make_int2(i1, i2);
    tk_w[t] = make_float2(p1 / wsum, p2 / wsum);
    token_slot[2 * t] = -1;
    token_slot[2 * t + 1] = -1;
  }
}

// ---------------- dispatch: per-expert FCFS capacity assignment (block scan)
__global__ void k_dispatch(const int2* __restrict__ tk_e, int* __restrict__ token_slot,
                           int* __restrict__ expert_tokens) {
  int e = blockIdx.x;
  int tid = threadIdx.x;
  int lane = tid & 63, w = tid >> 6;
  __shared__ int wave_cnt[4];
  int base = 0;
  for (int chunk = 0; chunk < NTOK / 256; ++chunk) {
    int t = chunk * 256 + tid;
    int2 te = tk_e[t];
    int k = (te.x == e) ? 0 : ((te.y == e) ? 1 : -1);
    bool flag = (k >= 0);
    unsigned long long m = __ballot(flag);
    int pre = __popcll(m & ((1ull << lane) - 1ull));
    __syncthreads();  // protect wave_cnt from previous iteration's readers
    if (lane == 0) wave_cnt[w] = __popcll(m);
    __syncthreads();
    int off = 0;
#pragma unroll
    for (int i = 0; i < 4; ++i) off += (i < w) ? wave_cnt[i] : 0;
    int total = wave_cnt[0] + wave_cnt[1] + wave_cnt[2] + wave_cnt[3];
    int rank = base + off + pre;
    if (flag && rank < CAP) {
      expert_tokens[e * CAP + rank] = t;
      token_slot[2 * t + k] = e * CAP + rank;
    }
    base += total;
  }
  int nvalid = base < CAP ? base : CAP;
  for (int s = nvalid + tid; s < CAP; s += 256)
    expert_tokens[e * CAP + s] = 0;  // padded slots: weight 0, never combined
}

// ---------------- GEMM1: h = gelu(gather(x) @ w1 + b1), bf16 MFMA 128x128 tile
__global__ __launch_bounds__(256) void k_gemm1(
    const float* __restrict__ x, const __hip_bfloat16* __restrict__ w1t,
    const float* __restrict__ b1, const int* __restrict__ expert_tokens,
    __hip_bfloat16* __restrict__ h) {
  __shared__ unsigned char AsB[128 * 128];
  __shared__ unsigned char BsB[128 * 128];
  int e = blockIdx.z, mt = blockIdx.y, nt = blockIdx.x;
  int m0 = mt * 128, n0 = nt * 128;
  int tid = threadIdx.x;
  int srow = tid >> 1, sseg = tid & 1;
  int tok = expert_tokens[e * CAP + m0 + srow];
  const float* asrc = x + (size_t)tok * DDIM + sseg * 32;
  const __hip_bfloat16* bsrc =
      w1t + (size_t)(e * HDIM + n0 + srow) * DDIM + sseg * 32;
  int wid = tid >> 6, lane = tid & 63;
  int wr = wid >> 1, wc = wid & 1;
  int lrow = lane & 15, lkb = (lane >> 4) * 16;
  f32x4 acc[4][4] = {};
  for (int k0 = 0; k0 < DDIM; k0 += 64) {
    const float4* ap = reinterpret_cast<const float4*>(asrc + k0);
#pragma unroll
    for (int i = 0; i < 4; ++i) {
      float4 u = ap[2 * i], v = ap[2 * i + 1];
      ushort8v o;
      o[0] = f2bf(u.x); o[1] = f2bf(u.y); o[2] = f2bf(u.z); o[3] = f2bf(u.w);
      o[4] = f2bf(v.x); o[5] = f2bf(v.y); o[6] = f2bf(v.z); o[7] = f2bf(v.w);
      *reinterpret_cast<ushort8v*>(AsB + swz(srow, sseg * 64 + i * 16)) = o;
    }
    const ushort8v* bp = reinterpret_cast<const ushort8v*>(bsrc + k0);
#pragma unroll
    for (int i = 0; i < 4; ++i)
      *reinterpret_cast<ushort8v*>(BsB + swz(srow, sseg * 64 + i * 16)) = bp[i];
    __syncthreads();
#pragma unroll
    for (int ks = 0; ks < 2; ++ks) {
      int kb = ks * 64 + lkb;
      short8v a[4], b[4];
#pragma unroll
      for (int mm = 0; mm < 4; ++mm)
        a[mm] = *reinterpret_cast<const short8v*>(
            AsB + swz(wr * 64 + mm * 16 + lrow, kb));
#pragma unroll
      for (int nn = 0; nn < 4; ++nn)
        b[nn] = *reinterpret_cast<const short8v*>(
            BsB + swz(wc * 64 + nn * 16 + lrow, kb));
#pragma unroll
      for (int mm = 0; mm < 4; ++mm)
#pragma unroll
        for (int nn = 0; nn < 4; ++nn)
          acc[mm][nn] = __builtin_amdgcn_mfma_f32_16x16x32_bf16(
              a[mm], b[nn], acc[mm][nn], 0, 0, 0);
    }
    __syncthreads();
  }
  int rb = m0 + wr * 64 + ((lane >> 4) << 2);
  int cb = n0 + wc * 64 + lrow;
#pragma unroll
  for (int nn = 0; nn < 4; ++nn) {
    int col = cb + nn * 16;
    float bias = b1[e * HDIM + col];
#pragma unroll
    for (int mm = 0; mm < 4; ++mm) {
      int row = rb + mm * 16;
#pragma unroll
      for (int j = 0; j < 4; ++j) {
        float v = acc[mm][nn][j] + bias;
        v = 0.5f * v * (1.0f + erff(v * 0.70710678118654752f));  // exact gelu
        h[(size_t)(e * CAP + row + j) * HDIM + col] = __float2bfloat16(v);
      }
    }
  }
}

// ---------------- GEMM2: out = h @ w2 + b2 (f32 out buffer)
__global__ __launch_bounds__(256) void k_gemm2(
    const __hip_bfloat16* __restrict__ h, const __hip_bfloat16* __restrict__ w2t,
    const float* __restrict__ b2, float* __restrict__ outbuf) {
  __shared__ unsigned char AsB[128 * 128];
  __shared__ unsigned char BsB[128 * 128];
  int e = blockIdx.z, mt = blockIdx.y, nt = blockIdx.x;
  int m0 = mt * 128, n0 = nt * 128;
  int tid = threadIdx.x;
  int srow = tid >> 1, sseg = tid & 1;
  const __hip_bfloat16* asrc =
      h + (size_t)(e * CAP + m0 + srow) * HDIM + sseg * 32;
  const __hip_bfloat16* bsrc =
      w2t + (size_t)(e * ODIM + n0 + srow) * HDIM + sseg * 32;
  int wid = tid >> 6, lane = tid & 63;
  int wr = wid >> 1, wc = wid & 1;
  int lrow = lane & 15, lkb = (lane >> 4) * 16;
  f32x4 acc[4][4] = {};
  for (int k0 = 0; k0 < HDIM; k0 += 64) {
    const ushort8v* ap = reinterpret_cast<const ushort8v*>(asrc + k0);
    const ushort8v* bp = reinterpret_cast<const ushort8v*>(bsrc + k0);
#pragma unroll
    for (int i = 0; i < 4; ++i)
      *reinterpret_cast<ushort8v*>(AsB + swz(srow, sseg * 64 + i * 16)) = ap[i];
#pragma unroll
    for (int i = 0; i < 4; ++i)
      *reinterpret_cast<ushort8v*>(BsB + swz(srow, sseg * 64 + i * 16)) = bp[i];
    __syncthreads();
#pragma unroll
    for (int ks = 0; ks < 2; ++ks) {
      int kb = ks * 64 + lkb;
      short8v a[4], b[4];
#pragma unroll
      for (int mm = 0; mm < 4; ++mm)
        a[mm] = *reinterpret_cast<const short8v*>(
            AsB + swz(wr * 64 + mm * 16 + lrow, kb));
#pragma unroll
      for (int nn = 0; nn < 4; ++nn)
        b[nn] = *reinterpret_cast<const short8v*>(
            BsB + swz(wc * 64 + nn * 16 + lrow, kb));
#pragma unroll
      for (int mm = 0; mm < 4; ++mm)
#pragma unroll
        for (int nn = 0; nn < 4; ++nn)
          acc[mm][nn] = __builtin_amdgcn_mfma_f32_16x16x32_bf16(
              a[mm], b[nn], acc[mm][nn], 0, 0, 0);
    }
    __syncthreads();
  }
  int rb = m0 + wr * 64 + ((lane >> 4) << 2);
  int cb = n0 + wc * 64 + lrow;
#pragma unroll
  for (int nn = 0; nn < 4; ++nn) {
    int col = cb + nn * 16;
    float bias = b2[e * ODIM + col];
#pragma unroll
    for (int mm = 0; mm < 4; ++mm) {
      int row = rb + mm * 16;
#pragma unroll
      for (int j = 0; j < 4; ++j)
        outbuf[(size_t)(e * CAP + row + j) * ODIM + col] = acc[mm][nn][j] + bias;
    }
  }
}

// ---------------- combine: per token, sum its <=2 weighted expert rows
__global__ void k_combine(const float* __restrict__ outbuf,
                          const int* __restrict__ token_slot,
                          const float2* __restrict__ tk_w,
                          float* __restrict__ comb) {
  int tid = threadIdx.x;
  int wid = tid >> 6, lane = tid & 63;
  int t = blockIdx.x * 4 + wid;
  int s0 = token_slot[2 * t], s1 = token_slot[2 * t + 1];
  float2 w = tk_w[t];
  float r[8] = {0.f, 0.f, 0.f, 0.f, 0.f, 0.f, 0.f, 0.f};
  if (s0 >= 0) {
    const float4* p = reinterpret_cast<const float4*>(outbuf + (size_t)s0 * ODIM + lane * 8);
    float4 a = p[0], b = p[1];
    r[0] += w.x * a.x; r[1] += w.x * a.y; r[2] += w.x * a.z; r[3] += w.x * a.w;
    r[4] += w.x * b.x; r[5] += w.x * b.y; r[6] += w.x * b.z; r[7] += w.x * b.w;
  }
  if (s1 >= 0) {
    const float4* p = reinterpret_cast<const float4*>(outbuf + (size_t)s1 * ODIM + lane * 8);
    float4 a = p[0], b = p[1];
    r[0] += w.y * a.x; r[1] += w.y * a.y; r[2] += w.y * a.z; r[3] += w.y * a.w;
    r[4] += w.y * b.x; r[5] += w.y * b.y; r[6] += w.y * b.z; r[7] += w.y * b.w;
  }
  float4* q = reinterpret_cast<float4*>(comb + (size_t)t * ODIM + lane * 8);
  float4 o0 = {r[0], r[1], r[2], r[3]};
  float4 o1 = {r[4], r[5], r[6], r[7]};
  q[0] = o0;
  q[1] = o1;
}

extern "C" void kernel_launch(void* const* d_in, const int* in_sizes, int n_in,
                              void* d_out, int out_size, void* d_ws, size_t ws_size,
                              hipStream_t stream) {
  const float* x      = (const float*)d_in[0];
  const float* gate_w = (const float*)d_in[1];
  const float* gate_b = (const float*)d_in[2];
  const float* w1     = (const float*)d_in[3];
  const float* b1     = (const float*)d_in[4];
  const float* w2     = (const float*)d_in[5];
  const float* b2     = (const float*)d_in[6];

  float* comb = (float*)d_out;                          // (8,2048,512) f32
  float* gate_probs = comb + (size_t)NTOK * ODIM;       // (16384,8) f32

  // workspace layout (needs ~128.5 MiB)
  char* ws = (char*)d_ws;
  __hip_bfloat16* w1t   = (__hip_bfloat16*)(ws);                 // 16 MiB (E,H,D)
  __hip_bfloat16* w2t   = (__hip_bfloat16*)(ws + 16777216);      // 16 MiB (E,O,H)
  __hip_bfloat16* hbuf  = (__hip_bfloat16*)(ws + 33554432);      // 64 MiB (E,CAP,H)
  float*          outbuf= (float*)(ws + 100663296);              // 32 MiB (E,CAP,O)
  int*   expert_tokens  = (int*)(ws + 134217728);                // 64 KiB
  int2*  tk_e           = (int2*)(ws + 134283264);               // 128 KiB
  float2* tk_w          = (float2*)(ws + 134414336);             // 128 KiB
  int*   token_slot     = (int*)(ws + 134545408);                // 128 KiB

  k_transpose_cvt<<<dim3(HDIM / 32, DDIM / 32, NE), dim3(32, 8), 0, stream>>>(w1, w1t, DDIM, HDIM);
  k_transpose_cvt<<<dim3(ODIM / 32, HDIM / 32, NE), dim3(32, 8), 0, stream>>>(w2, w2t, HDIM, ODIM);
  k_gate<<<NTOK / 4, 256, 0, stream>>>(x, gate_w, gate_b, gate_probs, tk_e, tk_w, token_slot);
  k_dispatch<<<NE, 256, 0, stream>>>(tk_e, token_slot, expert_tokens);
  k_gemm1<<<dim3(HDIM / 128, CAP / 128, NE), 256, 0, stream>>>(x, w1t, b1, expert_tokens, hbuf);
  k_gemm2<<<dim3(ODIM / 128, CAP / 128, NE), 256, 0, stream>>>(hbuf, w2t, b2, outbuf);
  k_combine<<<NTOK / 4, 256, 0, stream>>>(outbuf, token_slot, tk_w, comb);
}

// Round 2
// 233.704 us; speedup vs baseline: 1.0739x; 1.0739x over previous
//
#include <hip/hip_runtime.h>
#include <hip/hip_bf16.h>

// Problem constants (SparseMoE: D=512, H=2048, O=512, E=8, K=2, CF=1.0)
#define NTOK 16384
#define DDIM 512
#define HDIM 2048
#define ODIM 512
#define NE 8
#define CAP 2048   // max(int(N/E*CF), 4) = 2048

typedef __attribute__((ext_vector_type(8))) short short8v;
typedef __attribute__((ext_vector_type(8))) unsigned short ushort8v;
typedef __attribute__((ext_vector_type(4))) float f32x4;

static __device__ __forceinline__ unsigned short f2bf(float f) {
  __hip_bfloat16 h = __float2bfloat16(f);
  return __builtin_bit_cast(unsigned short, h);
}

template <typename T> __device__ __forceinline__ T cvt_out(float v);
template <> __device__ __forceinline__ float cvt_out<float>(float v) { return v; }
template <> __device__ __forceinline__ __hip_bfloat16 cvt_out<__hip_bfloat16>(float v) {
  return __float2bfloat16(v);
}

// async global->LDS, 16B per lane; LDS dest = wave-uniform base + lane*16
#define GLOAD_LDS16(gp, lp)                                               \
  __builtin_amdgcn_global_load_lds(                                       \
      (const __attribute__((address_space(1))) void*)(gp),                \
      (__attribute__((address_space(3))) void*)(lp), 16, 0, 0)

// ---------------- transpose + f32->bf16 convert: (E,R,C) f32 -> (E,C,R) bf16
__global__ void k_transpose_cvt(const float* __restrict__ src,
                                __hip_bfloat16* __restrict__ dst, int R, int C) {
  __shared__ float tile[32][33];
  int e = blockIdx.z;
  size_t base = (size_t)e * R * C;
  int c0 = blockIdx.x * 32, r0 = blockIdx.y * 32;
  int tx = threadIdx.x, ty = threadIdx.y;
#pragma unroll
  for (int i = 0; i < 32; i += 8)
    tile[ty + i][tx] = src[base + (size_t)(r0 + ty + i) * C + c0 + tx];
  __syncthreads();
#pragma unroll
  for (int i = 0; i < 32; i += 8)
    dst[base + (size_t)(c0 + ty + i) * R + r0 + tx] = __float2bfloat16(tile[tx][ty + i]);
}

// ---------------- gating: logits, softmax (f32), top-2 + normalized weights
__global__ void k_gate(const float* __restrict__ x, const float* __restrict__ gw,
                       const float* __restrict__ gb, float* __restrict__ gate_probs,
                       int2* __restrict__ tk_e, float2* __restrict__ tk_w,
                       int* __restrict__ token_slot) {
  __shared__ float gws[DDIM * 9];  // pad 8->9 floats per row: bank-conflict-free
  int tid = threadIdx.x;
  for (int i = tid; i < DDIM * NE; i += 256) {
    int d = i >> 3, e = i & 7;
    gws[d * 9 + e] = gw[i];
  }
  __syncthreads();
  int wid = tid >> 6, lane = tid & 63;
  int t = blockIdx.x * 4 + wid;
  const float* xr = x + (size_t)t * DDIM;
  float acc[NE] = {0.f, 0.f, 0.f, 0.f, 0.f, 0.f, 0.f, 0.f};
#pragma unroll
  for (int j = 0; j < 8; ++j) {
    float xv = xr[lane + 64 * j];
    const float* g = &gws[(lane + 64 * j) * 9];
#pragma unroll
    for (int e = 0; e < NE; ++e) acc[e] += xv * g[e];
  }
#pragma unroll
  for (int e = 0; e < NE; ++e) {
#pragma unroll
    for (int off = 32; off > 0; off >>= 1) acc[e] += __shfl_xor(acc[e], off, 64);
  }
  if (lane == 0) {
    float p[NE];
    float m = -1e30f;
#pragma unroll
    for (int e = 0; e < NE; ++e) { p[e] = acc[e] + gb[e]; m = fmaxf(m, p[e]); }
    float s = 0.f;
#pragma unroll
    for (int e = 0; e < NE; ++e) { p[e] = expf(p[e] - m); s += p[e]; }
    float inv = 1.f / s;
#pragma unroll
    for (int e = 0; e < NE; ++e) { p[e] *= inv; gate_probs[(size_t)t * NE + e] = p[e]; }
    int i1 = 0; float p1 = p[0];
#pragma unroll
    for (int e = 1; e < NE; ++e) if (p[e] > p1) { p1 = p[e]; i1 = e; }
    int i2 = -1; float p2 = -1e30f;
#pragma unroll
    for (int e = 0; e < NE; ++e) if (e != i1 && p[e] > p2) { p2 = p[e]; i2 = e; }
    float wsum = p1 + p2;
    tk_e[t] = make_int2(i1, i2);
    tk_w[t] = make_float2(p1 / wsum, p2 / wsum);
    token_slot[2 * t] = -1;
    token_slot[2 * t + 1] = -1;
  }
}

// ---------------- dispatch: per-expert FCFS capacity assignment (block scan)
__global__ void k_dispatch(const int2* __restrict__ tk_e, int* __restrict__ token_slot,
                           int* __restrict__ expert_tokens) {
  int e = blockIdx.x;
  int tid = threadIdx.x;
  int lane = tid & 63, w = tid >> 6;
  __shared__ int wave_cnt[4];
  int base = 0;
  for (int chunk = 0; chunk < NTOK / 256; ++chunk) {
    int t = chunk * 256 + tid;
    int2 te = tk_e[t];
    int k = (te.x == e) ? 0 : ((te.y == e) ? 1 : -1);
    bool flag = (k >= 0);
    unsigned long long m = __ballot(flag);
    int pre = __popcll(m & ((1ull << lane) - 1ull));
    __syncthreads();
    if (lane == 0) wave_cnt[w] = __popcll(m);
    __syncthreads();
    int off = 0;
#pragma unroll
    for (int i = 0; i < 4; ++i) off += (i < w) ? wave_cnt[i] : 0;
    int total = wave_cnt[0] + wave_cnt[1] + wave_cnt[2] + wave_cnt[3];
    int rank = base + off + pre;
    if (flag && rank < CAP) {
      expert_tokens[e * CAP + rank] = t;
      token_slot[2 * t + k] = e * CAP + rank;
    }
    base += total;
  }
  int nvalid = base < CAP ? base : CAP;
  for (int s = nvalid + tid; s < CAP; s += 256)
    expert_tokens[e * CAP + s] = 0;  // padded slots: weight 0, never combined
}

// ---------------- gather: xg[e][c][:] = bf16(x[expert_tokens[e*CAP+c]][:])
__global__ void k_gather(const float* __restrict__ x,
                         const int* __restrict__ expert_tokens,
                         __hip_bfloat16* __restrict__ xg) {
  int tid = threadIdx.x, wid = tid >> 6, lane = tid & 63;
  int slot = blockIdx.x * 4 + wid;  // 0..E*CAP-1
  int tok = expert_tokens[slot];
  const float4* src = reinterpret_cast<const float4*>(x + (size_t)tok * DDIM) + lane * 2;
  float4 u = src[0], v = src[1];
  ushort8v o;
  o[0] = f2bf(u.x); o[1] = f2bf(u.y); o[2] = f2bf(u.z); o[3] = f2bf(u.w);
  o[4] = f2bf(v.x); o[5] = f2bf(v.y); o[6] = f2bf(v.z); o[7] = f2bf(v.w);
  *reinterpret_cast<ushort8v*>(xg + (size_t)slot * DDIM + lane * 8) = o;
}

// ---------------- m97-structure GEMM: 128x128 tile, BK=32, global_load_lds.
// LDS linear [128][32] bf16 (64B rows); bank-conflict fix per rule #21:
// linear LDS dest + inverse-swizzled GLOBAL source + swizzled ds_read:
//   16B-slot s of row holds global k16 = s ^ ((row>>1)&3)  (XOR involution)
template <bool GELU, typename OutT>
__global__ __launch_bounds__(256) void k_gemm(
    const __hip_bfloat16* __restrict__ A,  // (E, CAP, K) row-major
    const __hip_bfloat16* __restrict__ B,  // (E, N,   K) row-major
    const float* __restrict__ bias,        // (E, N)
    OutT* __restrict__ C,                  // (E, CAP, N)
    int K, int N) {
  __shared__ __hip_bfloat16 As[128 * 32];
  __shared__ __hip_bfloat16 Bs[128 * 32];
  const int e = blockIdx.z, mt = blockIdx.y, nt = blockIdx.x;
  const int m0 = mt * 128, n0 = nt * 128;
  const int tid = threadIdx.x;
  const int lane = tid & 63, wid = tid >> 6;
  const int wr = wid >> 1, wc = wid & 1;
  const int lrow = lane & 15, kseg = lane >> 4;

  // staging: chunk c = r*256+tid -> row=c>>2, lds 16B-slot = tid&3
  const int r0 = tid >> 2;                       // rows 0..63 (round 0)
  const int sc = (tid & 3) ^ ((r0 >> 1) & 3);    // inverse-swizzled source k16
  const int cb0 = (tid & 192) * 16;              // wave-uniform LDS byte base
  const int cb1 = 256 * 16 + cb0;
  const __hip_bfloat16* Ab = A + ((size_t)e * CAP + m0) * K;
  const __hip_bfloat16* Bb = B + ((size_t)e * N + n0) * K;
  char* AsB = (char*)As;
  char* BsB = (char*)Bs;

  f32x4 acc[4][4] = {};
  for (int k0 = 0; k0 < K; k0 += 32) {
    GLOAD_LDS16(Ab + (size_t)r0 * K + k0 + sc * 8, AsB + cb0);
    GLOAD_LDS16(Bb + (size_t)r0 * K + k0 + sc * 8, BsB + cb0);
    GLOAD_LDS16(Ab + (size_t)(r0 + 64) * K + k0 + sc * 8, AsB + cb1);
    GLOAD_LDS16(Bb + (size_t)(r0 + 64) * K + k0 + sc * 8, BsB + cb1);
    __syncthreads();  // drains vmcnt(0): gload_lds complete
    short8v a[4], b[4];
#pragma unroll
    for (int mm = 0; mm < 4; ++mm) {
      int rr = wr * 64 + mm * 16 + lrow;
      int ks = kseg ^ ((rr >> 1) & 3);
      a[mm] = *reinterpret_cast<const short8v*>(AsB + rr * 64 + ks * 16);
    }
#pragma unroll
    for (int nn = 0; nn < 4; ++nn) {
      int rr = wc * 64 + nn * 16 + lrow;
      int ks = kseg ^ ((rr >> 1) & 3);
      b[nn] = *reinterpret_cast<const short8v*>(BsB + rr * 64 + ks * 16);
    }
#pragma unroll
    for (int mm = 0; mm < 4; ++mm)
#pragma unroll
      for (int nn = 0; nn < 4; ++nn)
        acc[mm][nn] = __builtin_amdgcn_mfma_f32_16x16x32_bf16(
            a[mm], b[nn], acc[mm][nn], 0, 0, 0);
    __syncthreads();
  }
  const int rb = m0 + wr * 64 + kseg * 4;
  const int cbase = n0 + wc * 64 + lrow;
#pragma unroll
  for (int nn = 0; nn < 4; ++nn) {
    int col = cbase + nn * 16;
    float bv = bias[e * N + col];
#pragma unroll
    for (int mm = 0; mm < 4; ++mm) {
#pragma unroll
      for (int j = 0; j < 4; ++j) {
        float v = acc[mm][nn][j] + bv;
        if (GELU) v = 0.5f * v * (1.0f + erff(v * 0.70710678118654752f));
        C[((size_t)e * CAP + rb + mm * 16 + j) * N + col] = cvt_out<OutT>(v);
      }
    }
  }
}

// ---------------- combine: per token, sum its <=2 weighted expert rows
__global__ void k_combine(const float* __restrict__ outbuf,
                          const int* __restrict__ token_slot,
                          const float2* __restrict__ tk_w,
                          float* __restrict__ comb) {
  int tid = threadIdx.x;
  int wid = tid >> 6, lane = tid & 63;
  int t = blockIdx.x * 4 + wid;
  int s0 = token_slot[2 * t], s1 = token_slot[2 * t + 1];
  float2 w = tk_w[t];
  float r[8] = {0.f, 0.f, 0.f, 0.f, 0.f, 0.f, 0.f, 0.f};
  if (s0 >= 0) {
    const float4* p = reinterpret_cast<const float4*>(outbuf + (size_t)s0 * ODIM + lane * 8);
    float4 a = p[0], b = p[1];
    r[0] += w.x * a.x; r[1] += w.x * a.y; r[2] += w.x * a.z; r[3] += w.x * a.w;
    r[4] += w.x * b.x; r[5] += w.x * b.y; r[6] += w.x * b.z; r[7] += w.x * b.w;
  }
  if (s1 >= 0) {
    const float4* p = reinterpret_cast<const float4*>(outbuf + (size_t)s1 * ODIM + lane * 8);
    float4 a = p[0], b = p[1];
    r[0] += w.y * a.x; r[1] += w.y * a.y; r[2] += w.y * a.z; r[3] += w.y * a.w;
    r[4] += w.y * b.x; r[5] += w.y * b.y; r[6] += w.y * b.z; r[7] += w.y * b.w;
  }
  float4* q = reinterpret_cast<float4*>(comb + (size_t)t * ODIM + lane * 8);
  float4 o0 = {r[0], r[1], r[2], r[3]};
  float4 o1 = {r[4], r[5], r[6], r[7]};
  q[0] = o0;
  q[1] = o1;
}

extern "C" void kernel_launch(void* const* d_in, const int* in_sizes, int n_in,
                              void* d_out, int out_size, void* d_ws, size_t ws_size,
                              hipStream_t stream) {
  const float* x      = (const float*)d_in[0];
  const float* gate_w = (const float*)d_in[1];
  const float* gate_b = (const float*)d_in[2];
  const float* w1     = (const float*)d_in[3];
  const float* b1     = (const float*)d_in[4];
  const float* w2     = (const float*)d_in[5];
  const float* b2     = (const float*)d_in[6];

  float* comb = (float*)d_out;                     // (8,2048,512) f32
  float* gate_probs = comb + (size_t)NTOK * ODIM;  // (16384,8) f32

  // workspace layout (~128.5 MiB; xg aliases outbuf - disjoint lifetimes)
  char* ws = (char*)d_ws;
  __hip_bfloat16* w1t    = (__hip_bfloat16*)(ws);              // [0,16M)   (E,H,D)
  __hip_bfloat16* w2t    = (__hip_bfloat16*)(ws + 16777216);   // [16,32M)  (E,O,H)
  __hip_bfloat16* hbuf   = (__hip_bfloat16*)(ws + 33554432);   // [32,96M)  (E,CAP,H)
  __hip_bfloat16* xg     = (__hip_bfloat16*)(ws + 100663296);  // [96,112M) (E,CAP,D)
  float*          outbuf = (float*)(ws + 100663296);           // [96,128M) (E,CAP,O)
  int*   expert_tokens   = (int*)(ws + 134217728);
  int2*  tk_e            = (int2*)(ws + 134283264);
  float2* tk_w           = (float2*)(ws + 134414336);
  int*   token_slot      = (int*)(ws + 134545408);

  k_transpose_cvt<<<dim3(HDIM / 32, DDIM / 32, NE), dim3(32, 8), 0, stream>>>(w1, w1t, DDIM, HDIM);
  k_transpose_cvt<<<dim3(ODIM / 32, HDIM / 32, NE), dim3(32, 8), 0, stream>>>(w2, w2t, HDIM, ODIM);
  k_gate<<<NTOK / 4, 256, 0, stream>>>(x, gate_w, gate_b, gate_probs, tk_e, tk_w, token_slot);
  k_dispatch<<<NE, 256, 0, stream>>>(tk_e, token_slot, expert_tokens);
  k_gather<<<NE * CAP / 4, 256, 0, stream>>>(x, expert_tokens, xg);
  k_gemm<true, __hip_bfloat16>
      <<<dim3(HDIM / 128, CAP / 128, NE), 256, 0, stream>>>(xg, w1t, b1, expert_tokens ? hbuf : hbuf, DDIM, HDIM);
  k_gemm<false, float>
      <<<dim3(ODIM / 128, CAP / 128, NE), 256, 0, stream>>>(hbuf, w2t, b2, outbuf, HDIM, ODIM);
  k_combine<<<NTOK / 4, 256, 0, stream>>>(outbuf, token_slot, tk_w, comb);
}

// Round 3
// 179.815 us; speedup vs baseline: 1.3957x; 1.2997x over previous
//
#include <hip/hip_runtime.h>
#include <hip/hip_bf16.h>

// Problem constants (SparseMoE: D=512, H=2048, O=512, E=8, K=2, CF=1.0)
#define NTOK 16384
#define DDIM 512
#define HDIM 2048
#define ODIM 512
#define NE 8
#define CAP 2048   // max(int(N/E*CF), 4) = 2048

typedef __attribute__((ext_vector_type(8))) short short8v;
typedef __attribute__((ext_vector_type(4))) short short4v;
typedef __attribute__((ext_vector_type(8))) unsigned short ushort8v;
typedef __attribute__((ext_vector_type(4))) float f32x4;

static __device__ __forceinline__ unsigned short f2bf(float f) {
  __hip_bfloat16 h = __float2bfloat16(f);
  return __builtin_bit_cast(unsigned short, h);
}

// async global->LDS, 16B per lane; LDS dest = wave-uniform base + lane*16
#define GLOAD_LDS16(gp, lp)                                               \
  __builtin_amdgcn_global_load_lds(                                       \
      (const __attribute__((address_space(1))) void*)(gp),                \
      (__attribute__((address_space(3))) void*)(lp), 16, 0, 0)

// ---------------- transpose + f32->bf16 convert: (E,R,C) f32 -> (E,C,R) bf16
__global__ void k_transpose_cvt(const float* __restrict__ src,
                                __hip_bfloat16* __restrict__ dst, int R, int C) {
  __shared__ float tile[32][33];
  int e = blockIdx.z;
  size_t base = (size_t)e * R * C;
  int c0 = blockIdx.x * 32, r0 = blockIdx.y * 32;
  int tx = threadIdx.x, ty = threadIdx.y;
#pragma unroll
  for (int i = 0; i < 32; i += 8)
    tile[ty + i][tx] = src[base + (size_t)(r0 + ty + i) * C + c0 + tx];
  __syncthreads();
#pragma unroll
  for (int i = 0; i < 32; i += 8)
    dst[base + (size_t)(c0 + ty + i) * R + r0 + tx] = __float2bfloat16(tile[tx][ty + i]);
}

// ---------------- gating: logits, softmax (f32), top-2 + normalized weights
__global__ void k_gate(const float* __restrict__ x, const float* __restrict__ gw,
                       const float* __restrict__ gb, float* __restrict__ gate_probs,
                       int2* __restrict__ tk_e, float2* __restrict__ tk_w,
                       int* __restrict__ token_slot) {
  __shared__ float gws[DDIM * 9];  // pad 8->9 floats per row: bank-conflict-free
  int tid = threadIdx.x;
  for (int i = tid; i < DDIM * NE; i += 256) {
    int d = i >> 3, e = i & 7;
    gws[d * 9 + e] = gw[i];
  }
  __syncthreads();
  int wid = tid >> 6, lane = tid & 63;
  int t = blockIdx.x * 4 + wid;
  const float* xr = x + (size_t)t * DDIM;
  float acc[NE] = {0.f, 0.f, 0.f, 0.f, 0.f, 0.f, 0.f, 0.f};
#pragma unroll
  for (int j = 0; j < 8; ++j) {
    float xv = xr[lane + 64 * j];
    const float* g = &gws[(lane + 64 * j) * 9];
#pragma unroll
    for (int e = 0; e < NE; ++e) acc[e] += xv * g[e];
  }
#pragma unroll
  for (int e = 0; e < NE; ++e) {
#pragma unroll
    for (int off = 32; off > 0; off >>= 1) acc[e] += __shfl_xor(acc[e], off, 64);
  }
  if (lane == 0) {
    float p[NE];
    float m = -1e30f;
#pragma unroll
    for (int e = 0; e < NE; ++e) { p[e] = acc[e] + gb[e]; m = fmaxf(m, p[e]); }
    float s = 0.f;
#pragma unroll
    for (int e = 0; e < NE; ++e) { p[e] = expf(p[e] - m); s += p[e]; }
    float inv = 1.f / s;
#pragma unroll
    for (int e = 0; e < NE; ++e) { p[e] *= inv; gate_probs[(size_t)t * NE + e] = p[e]; }
    int i1 = 0; float p1 = p[0];
#pragma unroll
    for (int e = 1; e < NE; ++e) if (p[e] > p1) { p1 = p[e]; i1 = e; }
    int i2 = -1; float p2 = -1e30f;
#pragma unroll
    for (int e = 0; e < NE; ++e) if (e != i1 && p[e] > p2) { p2 = p[e]; i2 = e; }
    float wsum = p1 + p2;
    tk_e[t] = make_int2(i1, i2);
    tk_w[t] = make_float2(p1 / wsum, p2 / wsum);
    token_slot[2 * t] = -1;
    token_slot[2 * t + 1] = -1;
  }
}

// ---------------- dispatch: per-expert FCFS capacity assignment (block scan)
__global__ void k_dispatch(const int2* __restrict__ tk_e, int* __restrict__ token_slot,
                           int* __restrict__ expert_tokens) {
  int e = blockIdx.x;
  int tid = threadIdx.x;
  int lane = tid & 63, w = tid >> 6;   // 16 waves
  __shared__ int wave_cnt[16];
  int base = 0;
  for (int chunk = 0; chunk < NTOK / 1024; ++chunk) {
    int t = chunk * 1024 + tid;
    int2 te = tk_e[t];
    int k = (te.x == e) ? 0 : ((te.y == e) ? 1 : -1);
    bool flag = (k >= 0);
    unsigned long long m = __ballot(flag);
    int pre = __popcll(m & ((1ull << lane) - 1ull));
    __syncthreads();
    if (lane == 0) wave_cnt[w] = __popcll(m);
    __syncthreads();
    int off = 0, total = 0;
#pragma unroll
    for (int i = 0; i < 16; ++i) {
      off += (i < w) ? wave_cnt[i] : 0;
      total += wave_cnt[i];
    }
    int rank = base + off + pre;
    if (flag && rank < CAP) {
      expert_tokens[e * CAP + rank] = t;
      token_slot[2 * t + k] = e * CAP + rank;
    }
    base += total;
  }
  int nvalid = base < CAP ? base : CAP;
  for (int s = nvalid + tid; s < CAP; s += 1024)
    expert_tokens[e * CAP + s] = 0;  // padded slots: weight 0, never combined
}

// ---------------- gather: xg[e][c][:] = bf16(x[expert_tokens[e*CAP+c]][:])
__global__ void k_gather(const float* __restrict__ x,
                         const int* __restrict__ expert_tokens,
                         __hip_bfloat16* __restrict__ xg) {
  int tid = threadIdx.x, wid = tid >> 6, lane = tid & 63;
  int slot = blockIdx.x * 4 + wid;  // 0..E*CAP-1
  int tok = expert_tokens[slot];
  const float4* src = reinterpret_cast<const float4*>(x + (size_t)tok * DDIM) + lane * 2;
  float4 u = src[0], v = src[1];
  ushort8v o;
  o[0] = f2bf(u.x); o[1] = f2bf(u.y); o[2] = f2bf(u.z); o[3] = f2bf(u.w);
  o[4] = f2bf(v.x); o[5] = f2bf(v.y); o[6] = f2bf(v.z); o[7] = f2bf(v.w);
  *reinterpret_cast<ushort8v*>(xg + (size_t)slot * DDIM + lane * 8) = o;
}

// sigmoid-form tanh-GELU: |err vs exact erf-gelu| < ~1e-3, safe for bf16 out
static __device__ __forceinline__ float gelu_fast(float v) {
  float z = 1.5957691216057308f * (v + 0.044715f * v * v * v);
  return v / (1.f + __expf(-z));
}

// ---------------- swapped-operand 2-phase GEMM: 128x128 tile, BK=32, dbuf.
// A = weights (E, M, K): fragment rows -> output features (vector stores)
// B = tokens  (E, CAP, K); C = (E, CAP, M) token-major.
// LDS linear [128][32] bf16; rule #21 swizzle: linear dest + inverse-swizzled
// global source + swizzled ds_read (16B slot s holds k16 = s ^ ((row>>1)&3)).
template <bool GELU, typename OutT>
__global__ __launch_bounds__(256) void k_gemm(
    const __hip_bfloat16* __restrict__ A, const __hip_bfloat16* __restrict__ B,
    const float* __restrict__ bias, OutT* __restrict__ C, int K, int M) {
  __shared__ char lds[2][2][8192];  // [buf][A/B][128 rows x 64B]
  // XCD-aware bijective remap: each XCD chunk = contiguous logical range
  int gx = gridDim.x, gy = gridDim.y;
  int lin = (blockIdx.z * gy + blockIdx.y) * gx + blockIdx.x;
  int total = gx * gy * (int)gridDim.z;  // multiple of 8
  int cpx = total >> 3;
  lin = (lin & 7) * cpx + (lin >> 3);
  int gxy = gx * gy;
  int e = lin / gxy;
  int rem = lin - e * gxy;
  int mt = rem / gx, nt = rem - mt * gx;

  const int m0 = mt * 128, n0 = nt * 128;
  const int tid = threadIdx.x;
  const int lane = tid & 63, wid = tid >> 6;
  const int wr = wid >> 1, wc = wid & 1;
  const int lrow = lane & 15, kseg = lane >> 4;

  const int r0 = tid >> 2;                     // staging row 0..63
  const int sc = (tid & 3) ^ ((r0 >> 1) & 3);  // inverse-swizzled source k16
  const int cb0 = (tid & 192) * 16;            // wave-uniform LDS byte base
  const int cb1 = 4096 + cb0;
  const __hip_bfloat16* Ab = A + ((size_t)e * M + m0) * K;
  const __hip_bfloat16* Bb = B + ((size_t)e * CAP + n0) * K;

#define STAGE(buf, kk)                                                      \
  do {                                                                      \
    GLOAD_LDS16(Ab + (size_t)r0 * K + (kk) + sc * 8, lds[buf][0] + cb0);    \
    GLOAD_LDS16(Ab + (size_t)(r0 + 64) * K + (kk) + sc * 8, lds[buf][0] + cb1); \
    GLOAD_LDS16(Bb + (size_t)r0 * K + (kk) + sc * 8, lds[buf][1] + cb0);    \
    GLOAD_LDS16(Bb + (size_t)(r0 + 64) * K + (kk) + sc * 8, lds[buf][1] + cb1); \
  } while (0)

  f32x4 acc[4][4] = {};
  STAGE(0, 0);
  __syncthreads();
  int cur = 0;
  for (int k0 = 0; k0 < K; k0 += 32) {
    if (k0 + 32 < K) {
      if (cur) STAGE(0, k0 + 32); else STAGE(1, k0 + 32);
    }
    const char* AsB = lds[cur][0];
    const char* BsB = lds[cur][1];
    short8v a[4], b[4];
#pragma unroll
    for (int mm = 0; mm < 4; ++mm) {
      int rr = wr * 64 + mm * 16 + lrow;
      int ks = kseg ^ ((rr >> 1) & 3);
      a[mm] = *reinterpret_cast<const short8v*>(AsB + rr * 64 + ks * 16);
    }
#pragma unroll
    for (int nn = 0; nn < 4; ++nn) {
      int rr = wc * 64 + nn * 16 + lrow;
      int ks = kseg ^ ((rr >> 1) & 3);
      b[nn] = *reinterpret_cast<const short8v*>(BsB + rr * 64 + ks * 16);
    }
#pragma unroll
    for (int mm = 0; mm < 4; ++mm)
#pragma unroll
      for (int nn = 0; nn < 4; ++nn)
        acc[mm][nn] = __builtin_amdgcn_mfma_f32_16x16x32_bf16(
            a[mm], b[nn], acc[mm][nn], 0, 0, 0);
    __syncthreads();  // drains prefetch (vmcnt 0) + everyone done reading cur
    cur ^= 1;
  }
#undef STAGE

  // epilogue: lane holds 4 consecutive output-features (rows of A) at one token
#pragma unroll
  for (int mm = 0; mm < 4; ++mm) {
    int mrow = m0 + wr * 64 + mm * 16 + kseg * 4;
    float4 bv = *reinterpret_cast<const float4*>(&bias[e * M + mrow]);
#pragma unroll
    for (int nn = 0; nn < 4; ++nn) {
      int token = n0 + wc * 64 + nn * 16 + lrow;
      float v0 = acc[mm][nn][0] + bv.x;
      float v1 = acc[mm][nn][1] + bv.y;
      float v2 = acc[mm][nn][2] + bv.z;
      float v3 = acc[mm][nn][3] + bv.w;
      if (GELU) {
        v0 = gelu_fast(v0); v1 = gelu_fast(v1);
        v2 = gelu_fast(v2); v3 = gelu_fast(v3);
      }
      OutT* cp = C + ((size_t)e * CAP + token) * M + mrow;
      if constexpr (__is_same(OutT, __hip_bfloat16)) {
        short4v o;
        o[0] = (short)f2bf(v0); o[1] = (short)f2bf(v1);
        o[2] = (short)f2bf(v2); o[3] = (short)f2bf(v3);
        *reinterpret_cast<short4v*>(cp) = o;  // 8B store
      } else {
        float4 o = {v0, v1, v2, v3};
        *reinterpret_cast<float4*>(cp) = o;   // 16B store
      }
    }
  }
}

// ---------------- combine: per token, sum its <=2 weighted expert rows
__global__ void k_combine(const float* __restrict__ outbuf,
                          const int* __restrict__ token_slot,
                          const float2* __restrict__ tk_w,
                          float* __restrict__ comb) {
  int tid = threadIdx.x;
  int wid = tid >> 6, lane = tid & 63;
  int t = blockIdx.x * 4 + wid;
  int s0 = token_slot[2 * t], s1 = token_slot[2 * t + 1];
  float2 w = tk_w[t];
  float r[8] = {0.f, 0.f, 0.f, 0.f, 0.f, 0.f, 0.f, 0.f};
  if (s0 >= 0) {
    const float4* p = reinterpret_cast<const float4*>(outbuf + (size_t)s0 * ODIM + lane * 8);
    float4 a = p[0], b = p[1];
    r[0] += w.x * a.x; r[1] += w.x * a.y; r[2] += w.x * a.z; r[3] += w.x * a.w;
    r[4] += w.x * b.x; r[5] += w.x * b.y; r[6] += w.x * b.z; r[7] += w.x * b.w;
  }
  if (s1 >= 0) {
    const float4* p = reinterpret_cast<const float4*>(outbuf + (size_t)s1 * ODIM + lane * 8);
    float4 a = p[0], b = p[1];
    r[0] += w.y * a.x; r[1] += w.y * a.y; r[2] += w.y * a.z; r[3] += w.y * a.w;
    r[4] += w.y * b.x; r[5] += w.y * b.y; r[6] += w.y * b.z; r[7] += w.y * b.w;
  }
  float4* q = reinterpret_cast<float4*>(comb + (size_t)t * ODIM + lane * 8);
  float4 o0 = {r[0], r[1], r[2], r[3]};
  float4 o1 = {r[4], r[5], r[6], r[7]};
  q[0] = o0;
  q[1] = o1;
}

extern "C" void kernel_launch(void* const* d_in, const int* in_sizes, int n_in,
                              void* d_out, int out_size, void* d_ws, size_t ws_size,
                              hipStream_t stream) {
  const float* x      = (const float*)d_in[0];
  const float* gate_w = (const float*)d_in[1];
  const float* gate_b = (const float*)d_in[2];
  const float* w1     = (const float*)d_in[3];
  const float* b1     = (const float*)d_in[4];
  const float* w2     = (const float*)d_in[5];
  const float* b2     = (const float*)d_in[6];

  float* comb = (float*)d_out;                     // (8,2048,512) f32
  float* gate_probs = comb + (size_t)NTOK * ODIM;  // (16384,8) f32

  // workspace layout (~128.5 MiB; xg aliases outbuf - disjoint lifetimes)
  char* ws = (char*)d_ws;
  __hip_bfloat16* w1t    = (__hip_bfloat16*)(ws);              // [0,16M)   (E,H,D)
  __hip_bfloat16* w2t    = (__hip_bfloat16*)(ws + 16777216);   // [16,32M)  (E,O,H)
  __hip_bfloat16* hbuf   = (__hip_bfloat16*)(ws + 33554432);   // [32,96M)  (E,CAP,H)
  __hip_bfloat16* xg     = (__hip_bfloat16*)(ws + 100663296);  // [96,112M) (E,CAP,D)
  float*          outbuf = (float*)(ws + 100663296);           // [96,128M) (E,CAP,O)
  int*   expert_tokens   = (int*)(ws + 134217728);
  int2*  tk_e            = (int2*)(ws + 134283264);
  float2* tk_w           = (float2*)(ws + 134414336);
  int*   token_slot      = (int*)(ws + 134545408);

  k_transpose_cvt<<<dim3(HDIM / 32, DDIM / 32, NE), dim3(32, 8), 0, stream>>>(w1, w1t, DDIM, HDIM);
  k_transpose_cvt<<<dim3(ODIM / 32, HDIM / 32, NE), dim3(32, 8), 0, stream>>>(w2, w2t, HDIM, ODIM);
  k_gate<<<NTOK / 4, 256, 0, stream>>>(x, gate_w, gate_b, gate_probs, tk_e, tk_w, token_slot);
  k_dispatch<<<NE, 1024, 0, stream>>>(tk_e, token_slot, expert_tokens);
  k_gather<<<NE * CAP / 4, 256, 0, stream>>>(x, expert_tokens, xg);
  // GEMM1: A=w1t (E,H,D) M=HDIM, B=xg, C=hbuf (E,CAP,H) bf16 + GELU
  k_gemm<true, __hip_bfloat16>
      <<<dim3(CAP / 128, HDIM / 128, NE), 256, 0, stream>>>(w1t, xg, b1, hbuf, DDIM, HDIM);
  // GEMM2: A=w2t (E,O,H) M=ODIM, B=hbuf, C=outbuf (E,CAP,O) f32
  k_gemm<false, float>
      <<<dim3(CAP / 128, ODIM / 128, NE), 256, 0, stream>>>(w2t, hbuf, b2, outbuf, HDIM, ODIM);
  k_combine<<<NTOK / 4, 256, 0, stream>>>(outbuf, token_slot, tk_w, comb);
}

// Round 4
// 179.657 us; speedup vs baseline: 1.3969x; 1.0009x over previous
//
#include <hip/hip_runtime.h>
#include <hip/hip_bf16.h>

// Problem constants (SparseMoE: D=512, H=2048, O=512, E=8, K=2, CF=1.0)
#define NTOK 16384
#define DDIM 512
#define HDIM 2048
#define ODIM 512
#define NE 8
#define CAP 2048   // max(int(N/E*CF), 4) = 2048

typedef __attribute__((ext_vector_type(8))) short short8v;
typedef __attribute__((ext_vector_type(4))) short short4v;
typedef __attribute__((ext_vector_type(8))) unsigned short ushort8v;
typedef __attribute__((ext_vector_type(4))) float f32x4;

static __device__ __forceinline__ unsigned short f2bf(float f) {
  __hip_bfloat16 h = __float2bfloat16(f);
  return __builtin_bit_cast(unsigned short, h);
}

// async global->LDS, 16B per lane; LDS dest = wave-uniform base + lane*16
#define GLOAD_LDS16(gp, lp)                                               \
  __builtin_amdgcn_global_load_lds(                                       \
      (const __attribute__((address_space(1))) void*)(gp),                \
      (__attribute__((address_space(3))) void*)(lp), 16, 0, 0)

// ---------------- transpose + f32->bf16 convert: (E,R,C) f32 -> (E,C,R) bf16
__global__ void k_transpose_cvt(const float* __restrict__ src,
                                __hip_bfloat16* __restrict__ dst, int R, int C) {
  __shared__ float tile[32][33];
  int e = blockIdx.z;
  size_t base = (size_t)e * R * C;
  int c0 = blockIdx.x * 32, r0 = blockIdx.y * 32;
  int tx = threadIdx.x, ty = threadIdx.y;
#pragma unroll
  for (int i = 0; i < 32; i += 8)
    tile[ty + i][tx] = src[base + (size_t)(r0 + ty + i) * C + c0 + tx];
  __syncthreads();
#pragma unroll
  for (int i = 0; i < 32; i += 8)
    dst[base + (size_t)(c0 + ty + i) * R + r0 + tx] = __float2bfloat16(tile[tx][ty + i]);
}

// ---------------- gating: logits, softmax (f32), top-2 + normalized weights
__global__ void k_gate(const float* __restrict__ x, const float* __restrict__ gw,
                       const float* __restrict__ gb, float* __restrict__ gate_probs,
                       int2* __restrict__ tk_e, float2* __restrict__ tk_w,
                       int* __restrict__ token_slot) {
  __shared__ float gws[DDIM * 9];  // pad 8->9 floats per row: bank-conflict-free
  int tid = threadIdx.x;
  for (int i = tid; i < DDIM * NE; i += 256) {
    int d = i >> 3, e = i & 7;
    gws[d * 9 + e] = gw[i];
  }
  __syncthreads();
  int wid = tid >> 6, lane = tid & 63;
  int t = blockIdx.x * 4 + wid;
  const float* xr = x + (size_t)t * DDIM;
  float acc[NE] = {0.f, 0.f, 0.f, 0.f, 0.f, 0.f, 0.f, 0.f};
#pragma unroll
  for (int j = 0; j < 8; ++j) {
    float xv = xr[lane + 64 * j];
    const float* g = &gws[(lane + 64 * j) * 9];
#pragma unroll
    for (int e = 0; e < NE; ++e) acc[e] += xv * g[e];
  }
#pragma unroll
  for (int e = 0; e < NE; ++e) {
#pragma unroll
    for (int off = 32; off > 0; off >>= 1) acc[e] += __shfl_xor(acc[e], off, 64);
  }
  if (lane == 0) {
    float p[NE];
    float m = -1e30f;
#pragma unroll
    for (int e = 0; e < NE; ++e) { p[e] = acc[e] + gb[e]; m = fmaxf(m, p[e]); }
    float s = 0.f;
#pragma unroll
    for (int e = 0; e < NE; ++e) { p[e] = expf(p[e] - m); s += p[e]; }
    float inv = 1.f / s;
#pragma unroll
    for (int e = 0; e < NE; ++e) { p[e] *= inv; gate_probs[(size_t)t * NE + e] = p[e]; }
    int i1 = 0; float p1 = p[0];
#pragma unroll
    for (int e = 1; e < NE; ++e) if (p[e] > p1) { p1 = p[e]; i1 = e; }
    int i2 = -1; float p2 = -1e30f;
#pragma unroll
    for (int e = 0; e < NE; ++e) if (e != i1 && p[e] > p2) { p2 = p[e]; i2 = e; }
    float wsum = p1 + p2;
    tk_e[t] = make_int2(i1, i2);
    tk_w[t] = make_float2(p1 / wsum, p2 / wsum);
    token_slot[2 * t] = -1;
    token_slot[2 * t + 1] = -1;
  }
}

// ---------------- dispatch: per-expert FCFS capacity assignment (block scan)
__global__ void k_dispatch(const int2* __restrict__ tk_e, int* __restrict__ token_slot,
                           int* __restrict__ expert_tokens) {
  int e = blockIdx.x;
  int tid = threadIdx.x;
  int lane = tid & 63, w = tid >> 6;   // 16 waves
  __shared__ int wave_cnt[16];
  int base = 0;
  for (int chunk = 0; chunk < NTOK / 1024; ++chunk) {
    int t = chunk * 1024 + tid;
    int2 te = tk_e[t];
    int k = (te.x == e) ? 0 : ((te.y == e) ? 1 : -1);
    bool flag = (k >= 0);
    unsigned long long m = __ballot(flag);
    int pre = __popcll(m & ((1ull << lane) - 1ull));
    __syncthreads();
    if (lane == 0) wave_cnt[w] = __popcll(m);
    __syncthreads();
    int off = 0, total = 0;
#pragma unroll
    for (int i = 0; i < 16; ++i) {
      off += (i < w) ? wave_cnt[i] : 0;
      total += wave_cnt[i];
    }
    int rank = base + off + pre;
    if (flag && rank < CAP) {
      expert_tokens[e * CAP + rank] = t;
      token_slot[2 * t + k] = e * CAP + rank;
    }
    base += total;
  }
  int nvalid = base < CAP ? base : CAP;
  for (int s = nvalid + tid; s < CAP; s += 1024)
    expert_tokens[e * CAP + s] = 0;  // padded slots: weight 0, never combined
}

// ---------------- gather: xg[e][c][:] = bf16(x[expert_tokens[e*CAP+c]][:])
__global__ void k_gather(const float* __restrict__ x,
                         const int* __restrict__ expert_tokens,
                         __hip_bfloat16* __restrict__ xg) {
  int tid = threadIdx.x, wid = tid >> 6, lane = tid & 63;
  int slot = blockIdx.x * 4 + wid;  // 0..E*CAP-1
  int tok = expert_tokens[slot];
  const float4* src = reinterpret_cast<const float4*>(x + (size_t)tok * DDIM) + lane * 2;
  float4 u = src[0], v = src[1];
  ushort8v o;
  o[0] = f2bf(u.x); o[1] = f2bf(u.y); o[2] = f2bf(u.z); o[3] = f2bf(u.w);
  o[4] = f2bf(v.x); o[5] = f2bf(v.y); o[6] = f2bf(v.z); o[7] = f2bf(v.w);
  *reinterpret_cast<ushort8v*>(xg + (size_t)slot * DDIM + lane * 8) = o;
}

// sigmoid-form tanh-GELU: |err vs exact erf-gelu| < ~1e-3, safe for bf16 out
static __device__ __forceinline__ float gelu_fast(float v) {
  float z = 1.5957691216057308f * (v + 0.044715f * v * v * v);
  return v / (1.f + __expf(-z));
}

// ---------------- swapped-operand pipelined GEMM: 128x128 tile, BK=32.
// 3 LDS buffers, 3 tiles in flight via global_load_lds, counted vmcnt (T4):
//   prologue stages t0,t1,t2; per iter: vmcnt(8)->barrier->ds_read->
//   lgkmcnt(0)+sched_barrier->barrier->stage(t+3 into just-read buf)->MFMA.
// Never drains vmcnt to 0 in steady state; tail peels vmcnt(4)/vmcnt(0).
// A = weights (E, M, K): fragment rows -> output features (vector stores)
// B = tokens  (E, CAP, K); C = (E, CAP, M) token-major.
// LDS linear [128][32] bf16; rule #21 swizzle: linear dest + inverse-swizzled
// global source + swizzled ds_read (16B slot s holds k16 = s ^ ((row>>1)&3)).
template <bool GELU, typename OutT>
__global__ __launch_bounds__(256) void k_gemm(
    const __hip_bfloat16* __restrict__ A, const __hip_bfloat16* __restrict__ B,
    const float* __restrict__ bias, OutT* __restrict__ C, int K, int M) {
  __shared__ char lds[3][16384];  // [buf][ A:8KB | B:8KB ], 48 KB total
  // XCD-aware bijective remap: each XCD chunk = contiguous logical range
  int gx = gridDim.x, gy = gridDim.y;
  int lin = (blockIdx.z * gy + blockIdx.y) * gx + blockIdx.x;
  int total = gx * gy * (int)gridDim.z;  // multiple of 8
  int cpx = total >> 3;
  lin = (lin & 7) * cpx + (lin >> 3);
  int gxy = gx * gy;
  int e = lin / gxy;
  int rem = lin - e * gxy;
  int mt = rem / gx, nt = rem - mt * gx;

  const int m0 = mt * 128, n0 = nt * 128;
  const int tid = threadIdx.x;
  const int lane = tid & 63, wid = tid >> 6;
  const int wr = wid >> 1, wc = wid & 1;
  const int lrow = lane & 15, kseg = lane >> 4;

  const int r0 = tid >> 2;                     // staging row 0..63
  const int sc = (tid & 3) ^ ((r0 >> 1) & 3);  // inverse-swizzled source k16
  const int cb0 = (tid & 192) * 16;            // wave-uniform LDS byte base
  const int cb1 = 4096 + cb0;
  const __hip_bfloat16* Ab = A + ((size_t)e * M + m0) * K;
  const __hip_bfloat16* Bb = B + ((size_t)e * CAP + n0) * K;

#define STAGE(buf, kk)                                                         \
  do {                                                                         \
    GLOAD_LDS16(Ab + (size_t)r0 * K + (kk) + sc * 8, lds[buf] + cb0);          \
    GLOAD_LDS16(Ab + (size_t)(r0 + 64) * K + (kk) + sc * 8, lds[buf] + cb1);   \
    GLOAD_LDS16(Bb + (size_t)r0 * K + (kk) + sc * 8, lds[buf] + 8192 + cb0);   \
    GLOAD_LDS16(Bb + (size_t)(r0 + 64) * K + (kk) + sc * 8, lds[buf] + 8192 + cb1); \
  } while (0)

  f32x4 acc[4][4] = {};
  const int T = K >> 5;          // K-tiles (16 or 64; always >= 3)
  STAGE(0, 0);
  STAGE(1, 32);
  STAGE(2, 64);
  int cur = 0;
  for (int t = 0; t < T; ++t) {
    // retire tile t only; keep t+1, t+2 (8 loads) in flight
    if (t < T - 2)       asm volatile("s_waitcnt vmcnt(8)" ::: "memory");
    else if (t == T - 2) asm volatile("s_waitcnt vmcnt(4)" ::: "memory");
    else                 asm volatile("s_waitcnt vmcnt(0)" ::: "memory");
    __builtin_amdgcn_s_barrier();  // tile t visible to all waves
    const char* AsB = lds[cur];
    const char* BsB = lds[cur] + 8192;
    short8v a[4], b[4];
#pragma unroll
    for (int mm = 0; mm < 4; ++mm) {
      int rr = wr * 64 + mm * 16 + lrow;
      int ks = kseg ^ ((rr >> 1) & 3);
      a[mm] = *reinterpret_cast<const short8v*>(AsB + rr * 64 + ks * 16);
    }
#pragma unroll
    for (int nn = 0; nn < 4; ++nn) {
      int rr = wc * 64 + nn * 16 + lrow;
      int ks = kseg ^ ((rr >> 1) & 3);
      b[nn] = *reinterpret_cast<const short8v*>(BsB + rr * 64 + ks * 16);
    }
    asm volatile("s_waitcnt lgkmcnt(0)" ::: "memory");  // my reads landed
    __builtin_amdgcn_sched_barrier(0);                  // rule #18 fence
    __builtin_amdgcn_s_barrier();                       // all waves' reads done
    if (t + 3 < T) STAGE(cur, (t + 3) << 5);            // overwrite-safe
    __builtin_amdgcn_s_setprio(1);
#pragma unroll
    for (int mm = 0; mm < 4; ++mm)
#pragma unroll
      for (int nn = 0; nn < 4; ++nn)
        acc[mm][nn] = __builtin_amdgcn_mfma_f32_16x16x32_bf16(
            a[mm], b[nn], acc[mm][nn], 0, 0, 0);
    __builtin_amdgcn_s_setprio(0);
    cur = (cur == 2) ? 0 : cur + 1;
  }
#undef STAGE

  // epilogue: lane holds 4 consecutive output-features (rows of A) at one token
#pragma unroll
  for (int mm = 0; mm < 4; ++mm) {
    int mrow = m0 + wr * 64 + mm * 16 + kseg * 4;
    float4 bv = *reinterpret_cast<const float4*>(&bias[e * M + mrow]);
#pragma unroll
    for (int nn = 0; nn < 4; ++nn) {
      int token = n0 + wc * 64 + nn * 16 + lrow;
      float v0 = acc[mm][nn][0] + bv.x;
      float v1 = acc[mm][nn][1] + bv.y;
      float v2 = acc[mm][nn][2] + bv.z;
      float v3 = acc[mm][nn][3] + bv.w;
      if (GELU) {
        v0 = gelu_fast(v0); v1 = gelu_fast(v1);
        v2 = gelu_fast(v2); v3 = gelu_fast(v3);
      }
      OutT* cp = C + ((size_t)e * CAP + token) * M + mrow;
      if constexpr (__is_same(OutT, __hip_bfloat16)) {
        short4v o;
        o[0] = (short)f2bf(v0); o[1] = (short)f2bf(v1);
        o[2] = (short)f2bf(v2); o[3] = (short)f2bf(v3);
        *reinterpret_cast<short4v*>(cp) = o;  // 8B store
      } else {
        float4 o = {v0, v1, v2, v3};
        *reinterpret_cast<float4*>(cp) = o;   // 16B store
      }
    }
  }
}

// ---------------- combine: per token, sum its <=2 weighted expert rows
__global__ void k_combine(const float* __restrict__ outbuf,
                          const int* __restrict__ token_slot,
                          const float2* __restrict__ tk_w,
                          float* __restrict__ comb) {
  int tid = threadIdx.x;
  int wid = tid >> 6, lane = tid & 63;
  int t = blockIdx.x * 4 + wid;
  int s0 = token_slot[2 * t], s1 = token_slot[2 * t + 1];
  float2 w = tk_w[t];
  float r[8] = {0.f, 0.f, 0.f, 0.f, 0.f, 0.f, 0.f, 0.f};
  if (s0 >= 0) {
    const float4* p = reinterpret_cast<const float4*>(outbuf + (size_t)s0 * ODIM + lane * 8);
    float4 a = p[0], b = p[1];
    r[0] += w.x * a.x; r[1] += w.x * a.y; r[2] += w.x * a.z; r[3] += w.x * a.w;
    r[4] += w.x * b.x; r[5] += w.x * b.y; r[6] += w.x * b.z; r[7] += w.x * b.w;
  }
  if (s1 >= 0) {
    const float4* p = reinterpret_cast<const float4*>(outbuf + (size_t)s1 * ODIM + lane * 8);
    float4 a = p[0], b = p[1];
    r[0] += w.y * a.x; r[1] += w.y * a.y; r[2] += w.y * a.z; r[3] += w.y * a.w;
    r[4] += w.y * b.x; r[5] += w.y * b.y; r[6] += w.y * b.z; r[7] += w.y * b.w;
  }
  float4* q = reinterpret_cast<float4*>(comb + (size_t)t * ODIM + lane * 8);
  float4 o0 = {r[0], r[1], r[2], r[3]};
  float4 o1 = {r[4], r[5], r[6], r[7]};
  q[0] = o0;
  q[1] = o1;
}

extern "C" void kernel_launch(void* const* d_in, const int* in_sizes, int n_in,
                              void* d_out, int out_size, void* d_ws, size_t ws_size,
                              hipStream_t stream) {
  const float* x      = (const float*)d_in[0];
  const float* gate_w = (const float*)d_in[1];
  const float* gate_b = (const float*)d_in[2];
  const float* w1     = (const float*)d_in[3];
  const float* b1     = (const float*)d_in[4];
  const float* w2     = (const float*)d_in[5];
  const float* b2     = (const float*)d_in[6];

  float* comb = (float*)d_out;                     // (8,2048,512) f32
  float* gate_probs = comb + (size_t)NTOK * ODIM;  // (16384,8) f32

  // workspace layout (~128.5 MiB; xg aliases outbuf - disjoint lifetimes)
  char* ws = (char*)d_ws;
  __hip_bfloat16* w1t    = (__hip_bfloat16*)(ws);              // [0,16M)   (E,H,D)
  __hip_bfloat16* w2t    = (__hip_bfloat16*)(ws + 16777216);   // [16,32M)  (E,O,H)
  __hip_bfloat16* hbuf   = (__hip_bfloat16*)(ws + 33554432);   // [32,96M)  (E,CAP,H)
  __hip_bfloat16* xg     = (__hip_bfloat16*)(ws + 100663296);  // [96,112M) (E,CAP,D)
  float*          outbuf = (float*)(ws + 100663296);           // [96,128M) (E,CAP,O)
  int*   expert_tokens   = (int*)(ws + 134217728);
  int2*  tk_e            = (int2*)(ws + 134283264);
  float2* tk_w           = (float2*)(ws + 134414336);
  int*   token_slot      = (int*)(ws + 134545408);

  k_transpose_cvt<<<dim3(HDIM / 32, DDIM / 32, NE), dim3(32, 8), 0, stream>>>(w1, w1t, DDIM, HDIM);
  k_transpose_cvt<<<dim3(ODIM / 32, HDIM / 32, NE), dim3(32, 8), 0, stream>>>(w2, w2t, HDIM, ODIM);
  k_gate<<<NTOK / 4, 256, 0, stream>>>(x, gate_w, gate_b, gate_probs, tk_e, tk_w, token_slot);
  k_dispatch<<<NE, 1024, 0, stream>>>(tk_e, token_slot, expert_tokens);
  k_gather<<<NE * CAP / 4, 256, 0, stream>>>(x, expert_tokens, xg);
  // GEMM1: A=w1t (E,H,D) M=HDIM, B=xg, C=hbuf (E,CAP,H) bf16 + GELU
  k_gemm<true, __hip_bfloat16>
      <<<dim3(CAP / 128, HDIM / 128, NE), 256, 0, stream>>>(w1t, xg, b1, hbuf, DDIM, HDIM);
  // GEMM2: A=w2t (E,O,H) M=ODIM, B=hbuf, C=outbuf (E,CAP,O) f32
  k_gemm<false, float>
      <<<dim3(CAP / 128, ODIM / 128, NE), 256, 0, stream>>>(w2t, hbuf, b2, outbuf, HDIM, ODIM);
  k_combine<<<NTOK / 4, 256, 0, stream>>>(outbuf, token_slot, tk_w, comb);
}

// Round 5
// 174.440 us; speedup vs baseline: 1.4387x; 1.0299x over previous
//
#include <hip/hip_runtime.h>
#include <hip/hip_bf16.h>

// Problem constants (SparseMoE: D=512, H=2048, O=512, E=8, K=2, CF=1.0)
#define NTOK 16384
#define DDIM 512
#define HDIM 2048
#define ODIM 512
#define NE 8
#define CAP 2048   // max(int(N/E*CF), 4) = 2048

typedef __attribute__((ext_vector_type(8))) short short8v;
typedef __attribute__((ext_vector_type(4))) short short4v;
typedef __attribute__((ext_vector_type(8))) unsigned short ushort8v;
typedef __attribute__((ext_vector_type(4))) float f32x4;

static __device__ __forceinline__ unsigned short f2bf(float f) {
  __hip_bfloat16 h = __float2bfloat16(f);
  return __builtin_bit_cast(unsigned short, h);
}

// async global->LDS, 16B per lane; LDS dest = wave-uniform base + lane*16
#define GLOAD_LDS16(gp, lp)                                               \
  __builtin_amdgcn_global_load_lds(                                       \
      (const __attribute__((address_space(1))) void*)(gp),                \
      (__attribute__((address_space(3))) void*)(lp), 16, 0, 0)

// ---------------- transpose + f32->bf16 convert: (E,R,C) f32 -> (E,C,R) bf16
__global__ void k_transpose_cvt(const float* __restrict__ src,
                                __hip_bfloat16* __restrict__ dst, int R, int C) {
  __shared__ float tile[32][33];
  int e = blockIdx.z;
  size_t base = (size_t)e * R * C;
  int c0 = blockIdx.x * 32, r0 = blockIdx.y * 32;
  int tx = threadIdx.x, ty = threadIdx.y;
#pragma unroll
  for (int i = 0; i < 32; i += 8)
    tile[ty + i][tx] = src[base + (size_t)(r0 + ty + i) * C + c0 + tx];
  __syncthreads();
#pragma unroll
  for (int i = 0; i < 32; i += 8)
    dst[base + (size_t)(c0 + ty + i) * R + r0 + tx] = __float2bfloat16(tile[tx][ty + i]);
}

// ---------------- gating: logits, softmax (f32), top-2 + normalized weights
__global__ void k_gate(const float* __restrict__ x, const float* __restrict__ gw,
                       const float* __restrict__ gb, float* __restrict__ gate_probs,
                       int2* __restrict__ tk_e, float2* __restrict__ tk_w,
                       int* __restrict__ token_slot) {
  __shared__ float gws[DDIM * 9];  // pad 8->9 floats per row: bank-conflict-free
  int tid = threadIdx.x;
  for (int i = tid; i < DDIM * NE; i += 256) {
    int d = i >> 3, e = i & 7;
    gws[d * 9 + e] = gw[i];
  }
  __syncthreads();
  int wid = tid >> 6, lane = tid & 63;
  int t = blockIdx.x * 4 + wid;
  const float* xr = x + (size_t)t * DDIM;
  float acc[NE] = {0.f, 0.f, 0.f, 0.f, 0.f, 0.f, 0.f, 0.f};
#pragma unroll
  for (int j = 0; j < 8; ++j) {
    float xv = xr[lane + 64 * j];
    const float* g = &gws[(lane + 64 * j) * 9];
#pragma unroll
    for (int e = 0; e < NE; ++e) acc[e] += xv * g[e];
  }
#pragma unroll
  for (int e = 0; e < NE; ++e) {
#pragma unroll
    for (int off = 32; off > 0; off >>= 1) acc[e] += __shfl_xor(acc[e], off, 64);
  }
  if (lane == 0) {
    float p[NE];
    float m = -1e30f;
#pragma unroll
    for (int e = 0; e < NE; ++e) { p[e] = acc[e] + gb[e]; m = fmaxf(m, p[e]); }
    float s = 0.f;
#pragma unroll
    for (int e = 0; e < NE; ++e) { p[e] = expf(p[e] - m); s += p[e]; }
    float inv = 1.f / s;
#pragma unroll
    for (int e = 0; e < NE; ++e) { p[e] *= inv; gate_probs[(size_t)t * NE + e] = p[e]; }
    int i1 = 0; float p1 = p[0];
#pragma unroll
    for (int e = 1; e < NE; ++e) if (p[e] > p1) { p1 = p[e]; i1 = e; }
    int i2 = -1; float p2 = -1e30f;
#pragma unroll
    for (int e = 0; e < NE; ++e) if (e != i1 && p[e] > p2) { p2 = p[e]; i2 = e; }
    float wsum = p1 + p2;
    tk_e[t] = make_int2(i1, i2);
    tk_w[t] = make_float2(p1 / wsum, p2 / wsum);
    token_slot[2 * t] = -1;
    token_slot[2 * t + 1] = -1;
  }
}

// ---------------- dispatch: per-expert FCFS capacity assignment (block scan)
__global__ void k_dispatch(const int2* __restrict__ tk_e, int* __restrict__ token_slot,
                           int* __restrict__ expert_tokens) {
  int e = blockIdx.x;
  int tid = threadIdx.x;
  int lane = tid & 63, w = tid >> 6;   // 16 waves
  __shared__ int wave_cnt[16];
  int base = 0;
  for (int chunk = 0; chunk < NTOK / 1024; ++chunk) {
    int t = chunk * 1024 + tid;
    int2 te = tk_e[t];
    int k = (te.x == e) ? 0 : ((te.y == e) ? 1 : -1);
    bool flag = (k >= 0);
    unsigned long long m = __ballot(flag);
    int pre = __popcll(m & ((1ull << lane) - 1ull));
    __syncthreads();
    if (lane == 0) wave_cnt[w] = __popcll(m);
    __syncthreads();
    int off = 0, total = 0;
#pragma unroll
    for (int i = 0; i < 16; ++i) {
      off += (i < w) ? wave_cnt[i] : 0;
      total += wave_cnt[i];
    }
    int rank = base + off + pre;
    if (flag && rank < CAP) {
      expert_tokens[e * CAP + rank] = t;
      token_slot[2 * t + k] = e * CAP + rank;
    }
    base += total;
  }
  int nvalid = base < CAP ? base : CAP;
  for (int s = nvalid + tid; s < CAP; s += 1024)
    expert_tokens[e * CAP + s] = 0;  // padded slots: weight 0, never combined
}

// ---------------- gather: xg[e][c][:] = bf16(x[expert_tokens[e*CAP+c]][:])
__global__ void k_gather(const float* __restrict__ x,
                         const int* __restrict__ expert_tokens,
                         __hip_bfloat16* __restrict__ xg) {
  int tid = threadIdx.x, wid = tid >> 6, lane = tid & 63;
  int slot = blockIdx.x * 4 + wid;  // 0..E*CAP-1
  int tok = expert_tokens[slot];
  const float4* src = reinterpret_cast<const float4*>(x + (size_t)tok * DDIM) + lane * 2;
  float4 u = src[0], v = src[1];
  ushort8v o;
  o[0] = f2bf(u.x); o[1] = f2bf(u.y); o[2] = f2bf(u.z); o[3] = f2bf(u.w);
  o[4] = f2bf(v.x); o[5] = f2bf(v.y); o[6] = f2bf(v.z); o[7] = f2bf(v.w);
  *reinterpret_cast<ushort8v*>(xg + (size_t)slot * DDIM + lane * 8) = o;
}

// sigmoid-form tanh-GELU: |err vs exact erf-gelu| < ~1e-3, safe for bf16 out
static __device__ __forceinline__ float gelu_fast(float v) {
  float z = 1.5957691216057308f * (v + 0.044715f * v * v * v);
  return v / (1.f + __expf(-z));
}

// ---------------- pipelined GEMM: 128x128 tile, BK=32, 3 LDS buffers,
// register ping-pong fragments. Per K-step (ONE barrier):
//   vmcnt(4, counted) -> barrier(tile t+1 visible) -> issue ds_read frags(t+1)
//   -> stage tile t+3 (into buf of t) -> sched_barrier -> MFMA frags(t)
//   -> lgkmcnt(0) -> sched_barrier (rule 18).
// LDS reads of t+1 and global stage of t+3 overlap MFMA of t.
// A = weights (E, M, K): fragment rows -> output features (vector stores)
// B = tokens  (E, CAP, K); C = (E, CAP, M) token-major.
// Swizzle per rule #21: linear gload_lds dest + inverse-swizzled global
// source + swizzled ds_read (16B slot s holds k16 = s ^ ((row>>1)&3)).
template <int K, int M, bool GELU, typename OutT>
__global__ __launch_bounds__(256, 3) void k_gemm(
    const __hip_bfloat16* __restrict__ A, const __hip_bfloat16* __restrict__ B,
    const float* __restrict__ bias, OutT* __restrict__ C) {
  __shared__ char lds[3][16384];  // [buf][ A:8KB | B:8KB ], 48 KB total
  // XCD-aware bijective remap: each XCD chunk = contiguous logical range
  int gx = gridDim.x, gy = gridDim.y;
  int lin = (blockIdx.z * gy + blockIdx.y) * gx + blockIdx.x;
  int total = gx * gy * (int)gridDim.z;  // multiple of 8
  int cpx = total >> 3;
  lin = (lin & 7) * cpx + (lin >> 3);
  int gxy = gx * gy;
  int e = lin / gxy;
  int rem = lin - e * gxy;
  int mt = rem / gx, nt = rem - mt * gx;

  const int m0 = mt * 128, n0 = nt * 128;
  const int tid = threadIdx.x;
  const int lane = tid & 63, wid = tid >> 6;
  const int wr = wid >> 1, wc = wid & 1;
  const int lrow = lane & 15, kseg = lane >> 4;

  const int r0 = tid >> 2;                     // staging row 0..63
  const int sc = (tid & 3) ^ ((r0 >> 1) & 3);  // inverse-swizzled source k16
  const int cb0 = (tid & 192) * 16;            // wave-uniform LDS byte base
  const int cb1 = 4096 + cb0;
  const __hip_bfloat16* Ab = A + ((size_t)e * M + m0) * K;
  const __hip_bfloat16* Bb = B + ((size_t)e * CAP + n0) * K;

#define STAGE(buf, kk)                                                         \
  do {                                                                         \
    GLOAD_LDS16(Ab + (size_t)r0 * K + (kk) + sc * 8, lds[buf] + cb0);          \
    GLOAD_LDS16(Ab + (size_t)(r0 + 64) * K + (kk) + sc * 8, lds[buf] + cb1);   \
    GLOAD_LDS16(Bb + (size_t)r0 * K + (kk) + sc * 8, lds[buf] + 8192 + cb0);   \
    GLOAD_LDS16(Bb + (size_t)(r0 + 64) * K + (kk) + sc * 8, lds[buf] + 8192 + cb1); \
  } while (0)

#define READF(fa, fb, bi)                                                      \
  do {                                                                         \
    const char* AsB_ = lds[bi];                                                \
    const char* BsB_ = lds[bi] + 8192;                                         \
    _Pragma("unroll")                                                          \
    for (int mm = 0; mm < 4; ++mm) {                                           \
      int rr = wr * 64 + mm * 16 + lrow;                                       \
      int ks = kseg ^ ((rr >> 1) & 3);                                         \
      fa[mm] = *reinterpret_cast<const short8v*>(AsB_ + rr * 64 + ks * 16);    \
    }                                                                          \
    _Pragma("unroll")                                                          \
    for (int nn = 0; nn < 4; ++nn) {                                           \
      int rr = wc * 64 + nn * 16 + lrow;                                       \
      int ks = kseg ^ ((rr >> 1) & 3);                                         \
      fb[nn] = *reinterpret_cast<const short8v*>(BsB_ + rr * 64 + ks * 16);    \
    }                                                                          \
  } while (0)

#define MFMA16(fa, fb)                                                         \
  do {                                                                         \
    __builtin_amdgcn_s_setprio(1);                                             \
    _Pragma("unroll")                                                          \
    for (int mm = 0; mm < 4; ++mm)                                             \
      _Pragma("unroll")                                                        \
      for (int nn = 0; nn < 4; ++nn)                                           \
        acc[mm][nn] = __builtin_amdgcn_mfma_f32_16x16x32_bf16(                 \
            fa[mm], fb[nn], acc[mm][nn], 0, 0, 0);                             \
    __builtin_amdgcn_s_setprio(0);                                             \
  } while (0)

#define LGKM0_FENCE()                                                          \
  do {                                                                         \
    asm volatile("s_waitcnt lgkmcnt(0)" ::: "memory");                         \
    __builtin_amdgcn_sched_barrier(0);                                         \
  } while (0)

  f32x4 acc[4][4] = {};
  short8v pa[4], pb[4], qa[4], qb[4];  // ping / pong fragment sets
  const int T = K >> 5;                // K-tiles: 16 (GEMM1) or 64 (GEMM2)

  STAGE(0, 0);
  STAGE(1, 32);
  STAGE(2, 64);
  asm volatile("s_waitcnt vmcnt(8)" ::: "memory");  // tile 0 resident
  __builtin_amdgcn_s_barrier();
  READF(pa, pb, 0);
  LGKM0_FENCE();

  int bt = 0;  // t % 3
  for (int t = 0; t < T; t += 2) {
    int b1 = (bt == 2) ? 0 : bt + 1;  // (t+1) % 3
    int b2 = (b1 == 2) ? 0 : b1 + 1;  // (t+2) % 3
    // ---- even step: make tile t+1 visible, read->pong, MFMA ping
    if (t + 2 < T) asm volatile("s_waitcnt vmcnt(4)" ::: "memory");
    else           asm volatile("s_waitcnt vmcnt(0)" ::: "memory");
    __builtin_amdgcn_s_barrier();
    READF(qa, qb, b1);
    if (t + 3 < T) STAGE(bt, (t + 3) * 32);
    __builtin_amdgcn_sched_barrier(0);  // reads+stage issue before MFMA
    MFMA16(pa, pb);
    LGKM0_FENCE();                      // pong landed; fence next MFMA
    // ---- odd step: make tile t+2 visible, read->ping, MFMA pong
    if (t + 2 < T) {
      if (t + 3 < T) asm volatile("s_waitcnt vmcnt(4)" ::: "memory");
      else           asm volatile("s_waitcnt vmcnt(0)" ::: "memory");
      __builtin_amdgcn_s_barrier();
      READF(pa, pb, b2);
      if (t + 4 < T) STAGE(b1, (t + 4) * 32);
      __builtin_amdgcn_sched_barrier(0);
    }
    MFMA16(qa, qb);
    LGKM0_FENCE();
    bt = b2;
  }
#undef STAGE
#undef READF
#undef MFMA16
#undef LGKM0_FENCE

  // epilogue: lane holds 4 consecutive output-features (rows of A) at one token
#pragma unroll
  for (int mm = 0; mm < 4; ++mm) {
    int mrow = m0 + wr * 64 + mm * 16 + kseg * 4;
    float4 bv = *reinterpret_cast<const float4*>(&bias[e * M + mrow]);
#pragma unroll
    for (int nn = 0; nn < 4; ++nn) {
      int token = n0 + wc * 64 + nn * 16 + lrow;
      float v0 = acc[mm][nn][0] + bv.x;
      float v1 = acc[mm][nn][1] + bv.y;
      float v2 = acc[mm][nn][2] + bv.z;
      float v3 = acc[mm][nn][3] + bv.w;
      if (GELU) {
        v0 = gelu_fast(v0); v1 = gelu_fast(v1);
        v2 = gelu_fast(v2); v3 = gelu_fast(v3);
      }
      OutT* cp = C + ((size_t)e * CAP + token) * M + mrow;
      if constexpr (__is_same(OutT, __hip_bfloat16)) {
        short4v o;
        o[0] = (short)f2bf(v0); o[1] = (short)f2bf(v1);
        o[2] = (short)f2bf(v2); o[3] = (short)f2bf(v3);
        *reinterpret_cast<short4v*>(cp) = o;  // 8B store
      } else {
        float4 o = {v0, v1, v2, v3};
        *reinterpret_cast<float4*>(cp) = o;   // 16B store
      }
    }
  }
}

// ---------------- combine: per token, sum its <=2 weighted expert rows
__global__ void k_combine(const float* __restrict__ outbuf,
                          const int* __restrict__ token_slot,
                          const float2* __restrict__ tk_w,
                          float* __restrict__ comb) {
  int tid = threadIdx.x;
  int wid = tid >> 6, lane = tid & 63;
  int t = blockIdx.x * 4 + wid;
  int s0 = token_slot[2 * t], s1 = token_slot[2 * t + 1];
  float2 w = tk_w[t];
  float r[8] = {0.f, 0.f, 0.f, 0.f, 0.f, 0.f, 0.f, 0.f};
  if (s0 >= 0) {
    const float4* p = reinterpret_cast<const float4*>(outbuf + (size_t)s0 * ODIM + lane * 8);
    float4 a = p[0], b = p[1];
    r[0] += w.x * a.x; r[1] += w.x * a.y; r[2] += w.x * a.z; r[3] += w.x * a.w;
    r[4] += w.x * b.x; r[5] += w.x * b.y; r[6] += w.x * b.z; r[7] += w.x * b.w;
  }
  if (s1 >= 0) {
    const float4* p = reinterpret_cast<const float4*>(outbuf + (size_t)s1 * ODIM + lane * 8);
    float4 a = p[0], b = p[1];
    r[0] += w.y * a.x; r[1] += w.y * a.y; r[2] += w.y * a.z; r[3] += w.y * a.w;
    r[4] += w.y * b.x; r[5] += w.y * b.y; r[6] += w.y * b.z; r[7] += w.y * b.w;
  }
  float4* q = reinterpret_cast<float4*>(comb + (size_t)t * ODIM + lane * 8);
  float4 o0 = {r[0], r[1], r[2], r[3]};
  float4 o1 = {r[4], r[5], r[6], r[7]};
  q[0] = o0;
  q[1] = o1;
}

extern "C" void kernel_launch(void* const* d_in, const int* in_sizes, int n_in,
                              void* d_out, int out_size, void* d_ws, size_t ws_size,
                              hipStream_t stream) {
  const float* x      = (const float*)d_in[0];
  const float* gate_w = (const float*)d_in[1];
  const float* gate_b = (const float*)d_in[2];
  const float* w1     = (const float*)d_in[3];
  const float* b1     = (const float*)d_in[4];
  const float* w2     = (const float*)d_in[5];
  const float* b2     = (const float*)d_in[6];

  float* comb = (float*)d_out;                     // (8,2048,512) f32
  float* gate_probs = comb + (size_t)NTOK * ODIM;  // (16384,8) f32

  // workspace layout (~128.5 MiB; xg aliases outbuf - disjoint lifetimes)
  char* ws = (char*)d_ws;
  __hip_bfloat16* w1t    = (__hip_bfloat16*)(ws);              // [0,16M)   (E,H,D)
  __hip_bfloat16* w2t    = (__hip_bfloat16*)(ws + 16777216);   // [16,32M)  (E,O,H)
  __hip_bfloat16* hbuf   = (__hip_bfloat16*)(ws + 33554432);   // [32,96M)  (E,CAP,H)
  __hip_bfloat16* xg     = (__hip_bfloat16*)(ws + 100663296);  // [96,112M) (E,CAP,D)
  float*          outbuf = (float*)(ws + 100663296);           // [96,128M) (E,CAP,O)
  int*   expert_tokens   = (int*)(ws + 134217728);
  int2*  tk_e            = (int2*)(ws + 134283264);
  float2* tk_w           = (float2*)(ws + 134414336);
  int*   token_slot      = (int*)(ws + 134545408);

  k_transpose_cvt<<<dim3(HDIM / 32, DDIM / 32, NE), dim3(32, 8), 0, stream>>>(w1, w1t, DDIM, HDIM);
  k_transpose_cvt<<<dim3(ODIM / 32, HDIM / 32, NE), dim3(32, 8), 0, stream>>>(w2, w2t, HDIM, ODIM);
  k_gate<<<NTOK / 4, 256, 0, stream>>>(x, gate_w, gate_b, gate_probs, tk_e, tk_w, token_slot);
  k_dispatch<<<NE, 1024, 0, stream>>>(tk_e, token_slot, expert_tokens);
  k_gather<<<NE * CAP / 4, 256, 0, stream>>>(x, expert_tokens, xg);
  // GEMM1: A=w1t (E,H,D) M=HDIM, B=xg, C=hbuf (E,CAP,H) bf16 + GELU
  k_gemm<DDIM, HDIM, true, __hip_bfloat16>
      <<<dim3(CAP / 128, HDIM / 128, NE), 256, 0, stream>>>(w1t, xg, b1, hbuf);
  // GEMM2: A=w2t (E,O,H) M=ODIM, B=hbuf, C=outbuf (E,CAP,O) f32
  k_gemm<HDIM, ODIM, false, float>
      <<<dim3(CAP / 128, ODIM / 128, NE), 256, 0, stream>>>(w2t, hbuf, b2, outbuf);
  k_combine<<<NTOK / 4, 256, 0, stream>>>(outbuf, token_slot, tk_w, comb);
}